// Round 1
// baseline (1869.604 us; speedup 1.0000x reference)
//
#include <hip/hip_runtime.h>
#include <cstdint>
#include <cstddef>

using bf16x8 = __attribute__((ext_vector_type(8))) short;
using f32x4  = __attribute__((ext_vector_type(4))) float;

constexpr int kB = 8192;
constexpr int kD = 1024;
constexpr int kE = 8;
constexpr int kH = 4096;
constexpr int kC = 10;

__device__ __forceinline__ unsigned short f2bf(float f) {
  unsigned int u = __float_as_uint(f);
  u += 0x7FFFu + ((u >> 16) & 1u);   // round-to-nearest-even (finite inputs)
  return (unsigned short)(u >> 16);
}

#define GLD16(gptr, lptr)                                                      \
  __builtin_amdgcn_global_load_lds(                                            \
      (const __attribute__((address_space(1))) void*)(gptr),                   \
      (__attribute__((address_space(3))) void*)(lptr), 16, 0, 0)

// ---------------- convert x: f32 -> bf16, 8 elems/thread ----------------
__global__ __launch_bounds__(256) void k_convert_x(const float* __restrict__ x,
                                                   unsigned short* __restrict__ xb) {
  const long i = ((long)blockIdx.x * 256 + threadIdx.x) * 8;
  float4 a = *reinterpret_cast<const float4*>(x + i);
  float4 b = *reinterpret_cast<const float4*>(x + i + 4);
  bf16x8 o;
  o[0] = (short)f2bf(a.x); o[1] = (short)f2bf(a.y);
  o[2] = (short)f2bf(a.z); o[3] = (short)f2bf(a.w);
  o[4] = (short)f2bf(b.x); o[5] = (short)f2bf(b.y);
  o[6] = (short)f2bf(b.z); o[7] = (short)f2bf(b.w);
  *reinterpret_cast<bf16x8*>(xb + i) = o;
}

// ------------- transpose+convert W [E][K][N] f32 -> Wt [E][N][K] bf16 -------------
__global__ __launch_bounds__(256) void k_transpose_w(const float* __restrict__ W,
                                                     unsigned short* __restrict__ Wt,
                                                     int K, int N) {
  __shared__ unsigned short tile[32][33];
  const int e = blockIdx.z;
  const int n0 = blockIdx.x * 32, k0 = blockIdx.y * 32;
  const int tx = threadIdx.x, ty = threadIdx.y;  // (32,8)
  const float* Wb = W + (size_t)e * K * N;
  unsigned short* Wtb = Wt + (size_t)e * N * K;
#pragma unroll
  for (int j = 0; j < 32; j += 8)
    tile[ty + j][tx] = f2bf(Wb[(size_t)(k0 + ty + j) * N + n0 + tx]);
  __syncthreads();
#pragma unroll
  for (int j = 0; j < 32; j += 8)
    Wtb[(size_t)(n0 + ty + j) * K + k0 + tx] = tile[tx][ty + j];
}

// ---------------- routing: softmax(x @ Wr + br), one wave per row ----------------
__global__ __launch_bounds__(256) void k_routing(const float* __restrict__ x,
                                                 const float* __restrict__ Wr,
                                                 const float* __restrict__ br,
                                                 float* __restrict__ r) {
  const int w = threadIdx.x >> 6, l = threadIdx.x & 63;
  const int b = blockIdx.x * 4 + w;
  const float* xr = x + (size_t)b * kD;
  float acc[kE];
#pragma unroll
  for (int e = 0; e < kE; ++e) acc[e] = 0.f;
  for (int d = l; d < kD; d += 64) {
    const float xv = xr[d];
    const float* wrow = Wr + d * kE;
#pragma unroll
    for (int e = 0; e < kE; ++e) acc[e] += xv * wrow[e];
  }
#pragma unroll
  for (int e = 0; e < kE; ++e) {
#pragma unroll
    for (int s = 32; s > 0; s >>= 1) acc[e] += __shfl_xor(acc[e], s);
    acc[e] += br[e];
  }
  float mx = acc[0];
#pragma unroll
  for (int e = 1; e < kE; ++e) mx = fmaxf(mx, acc[e]);
  float sum = 0.f;
#pragma unroll
  for (int e = 0; e < kE; ++e) { acc[e] = expf(acc[e] - mx); sum += acc[e]; }
  const float inv = 1.f / sum;
  float val = 0.f;
#pragma unroll
  for (int e = 0; e < kE; ++e) if (l == e) val = acc[e] * inv;
  if (l < kE) r[(size_t)b * kE + l] = val;
}

// ---------------- m97-style 128x128 bf16 GEMM core (A[M,K] x Bt[N,K]) ----------------
__device__ __forceinline__ void gemm_core(const unsigned short* __restrict__ A,
                                          const unsigned short* __restrict__ Bt,
                                          int K, unsigned short* As, unsigned short* Bs,
                                          int brow, int bcol, f32x4 acc[4][4]) {
  const int tid = threadIdx.x;
  const int w = tid >> 6, l = tid & 63;
  const int wr = w >> 1, wc = w & 1;
  const int srow = tid >> 2;        // 0..63, row within staging round
  const int scol = (tid & 3) * 8;   // k-offset of the 8-elem chunk
  const size_t arow0 = (size_t)(brow + srow) * K + scol;
  const size_t arow1 = (size_t)(brow + 64 + srow) * K + scol;
  const size_t brow0 = (size_t)(bcol + srow) * K + scol;
  const size_t brow1 = (size_t)(bcol + 64 + srow) * K + scol;
  unsigned short* ldsA0 = As + (w * 64) * 8;          // wave-uniform LDS bases
  unsigned short* ldsA1 = As + (256 + w * 64) * 8;
  unsigned short* ldsB0 = Bs + (w * 64) * 8;
  unsigned short* ldsB1 = Bs + (256 + w * 64) * 8;

  for (int kt = 0; kt < K; kt += 32) {
    GLD16(A + arow0 + kt, ldsA0);
    GLD16(A + arow1 + kt, ldsA1);
    GLD16(Bt + brow0 + kt, ldsB0);
    GLD16(Bt + brow1 + kt, ldsB1);
    __syncthreads();   // drains vmcnt: LDS tiles valid
    bf16x8 af[4], bfr[4];
#pragma unroll
    for (int m = 0; m < 4; ++m)
      af[m] = *reinterpret_cast<const bf16x8*>(As + (wr * 64 + m * 16 + (l & 15)) * 32 + ((l >> 4) * 8));
#pragma unroll
    for (int n = 0; n < 4; ++n)
      bfr[n] = *reinterpret_cast<const bf16x8*>(Bs + (wc * 64 + n * 16 + (l & 15)) * 32 + ((l >> 4) * 8));
#pragma unroll
    for (int m = 0; m < 4; ++m)
#pragma unroll
      for (int n = 0; n < 4; ++n)
        acc[m][n] = __builtin_amdgcn_mfma_f32_16x16x32_bf16(af[m], bfr[n], acc[m][n], 0, 0, 0);
    __syncthreads();   // compute done before next stage overwrites
  }
}

// ---------------- GEMM1: h' = r[:,e] * relu(x @ W1[e] + b1[e]) -> bf16 ----------------
__global__ __launch_bounds__(256) void k_gemm1(const unsigned short* __restrict__ xb,
                                               const unsigned short* __restrict__ W1t,
                                               const float* __restrict__ b1,
                                               const float* __restrict__ rr,
                                               unsigned short* __restrict__ h,
                                               int e0, size_t hstride) {
  __shared__ __align__(16) unsigned short As[128 * 32];
  __shared__ __align__(16) unsigned short Bs[128 * 32];
  const int e = e0 + blockIdx.z;
  const int brow = blockIdx.x * 128, bcol = blockIdx.y * 128;
  f32x4 acc[4][4];
#pragma unroll
  for (int m = 0; m < 4; ++m)
#pragma unroll
    for (int n = 0; n < 4; ++n) acc[m][n] = (f32x4){0.f, 0.f, 0.f, 0.f};

  gemm_core(xb, W1t + (size_t)e * kH * kD, kD, As, Bs, brow, bcol, acc);

  const int l = threadIdx.x & 63, w = threadIdx.x >> 6;
  const int wr = w >> 1, wc = w & 1;
  unsigned short* hb = h + (size_t)blockIdx.z * hstride;
#pragma unroll
  for (int m = 0; m < 4; ++m) {
    const int r0 = brow + wr * 64 + m * 16 + ((l >> 4) * 4);
#pragma unroll
    for (int n = 0; n < 4; ++n) {
      const int col = bcol + wc * 64 + n * 16 + (l & 15);
      const float bias = b1[e * kH + col];
#pragma unroll
      for (int j = 0; j < 4; ++j) {
        const int row = r0 + j;
        float v = acc[m][n][j] + bias;
        v = fmaxf(v, 0.f) * rr[(size_t)row * kE + e];
        hb[(size_t)row * kH + col] = f2bf(v);
      }
    }
  }
}

// ------- GEMM2: out (+)= sum_e h'_e @ W2[e]  (+ sum_e r[b,e]*b2[e,:] on store) -------
template <int MODE>  // 0: store with bias-sum; 1: accumulate
__global__ __launch_bounds__(256) void k_gemm2(const unsigned short* __restrict__ h,
                                               const unsigned short* __restrict__ W2t,
                                               const float* __restrict__ b2,
                                               const float* __restrict__ rr,
                                               float* __restrict__ out, int e0, int ne) {
  __shared__ __align__(16) unsigned short As[128 * 32];
  __shared__ __align__(16) unsigned short Bs[128 * 32];
  const int brow = blockIdx.x * 128, bcol = blockIdx.y * 128;
  f32x4 acc[4][4];
#pragma unroll
  for (int m = 0; m < 4; ++m)
#pragma unroll
    for (int n = 0; n < 4; ++n) acc[m][n] = (f32x4){0.f, 0.f, 0.f, 0.f};

  for (int ee = 0; ee < ne; ++ee)
    gemm_core(h + (size_t)ee * kB * kH, W2t + (size_t)(e0 + ee) * kD * kH, kH,
              As, Bs, brow, bcol, acc);

  const int l = threadIdx.x & 63, w = threadIdx.x >> 6;
  const int wr = w >> 1, wc = w & 1;
#pragma unroll
  for (int m = 0; m < 4; ++m) {
    const int r0 = brow + wr * 64 + m * 16 + ((l >> 4) * 4);
#pragma unroll
    for (int n = 0; n < 4; ++n) {
      const int col = bcol + wc * 64 + n * 16 + (l & 15);
#pragma unroll
      for (int j = 0; j < 4; ++j) {
        const int row = r0 + j;
        float v = acc[m][n][j];
        if (MODE == 0) {
          float bt = 0.f;
#pragma unroll
          for (int e = 0; e < kE; ++e) bt += rr[(size_t)row * kE + e] * b2[e * kD + col];
          out[(size_t)row * kD + col] = v + bt;
        } else {
          out[(size_t)row * kD + col] += v;
        }
      }
    }
  }
}

// ---------------- final: y = out @ Wc + bc, one wave per row ----------------
__global__ __launch_bounds__(256) void k_final(const float* __restrict__ out,
                                               const float* __restrict__ Wc,
                                               const float* __restrict__ bc,
                                               float* __restrict__ y) {
  const int w = threadIdx.x >> 6, l = threadIdx.x & 63;
  const int b = blockIdx.x * 4 + w;
  const float* orow = out + (size_t)b * kD;
  float acc[kC];
#pragma unroll
  for (int c = 0; c < kC; ++c) acc[c] = 0.f;
#pragma unroll
  for (int p = 0; p < 4; ++p) {
    const int d = (p * 64 + l) * 4;
    float4 v = *reinterpret_cast<const float4*>(orow + d);
#pragma unroll
    for (int c = 0; c < kC; ++c) {
      acc[c] += v.x * Wc[(d + 0) * kC + c] + v.y * Wc[(d + 1) * kC + c] +
                v.z * Wc[(d + 2) * kC + c] + v.w * Wc[(d + 3) * kC + c];
    }
  }
#pragma unroll
  for (int c = 0; c < kC; ++c)
#pragma unroll
    for (int s = 32; s > 0; s >>= 1) acc[c] += __shfl_xor(acc[c], s);
  float ov = 0.f;
#pragma unroll
  for (int c = 0; c < kC; ++c) if (l == c) ov = acc[c];
  if (l < kC) y[(size_t)b * kC + l] = ov + bc[l];
}

extern "C" void kernel_launch(void* const* d_in, const int* in_sizes, int n_in,
                              void* d_out, int out_size, void* d_ws, size_t ws_size,
                              hipStream_t stream) {
  (void)in_sizes; (void)n_in; (void)out_size;
  const float* x  = (const float*)d_in[0];
  const float* Wr = (const float*)d_in[1];
  const float* br = (const float*)d_in[2];
  const float* W1 = (const float*)d_in[3];
  const float* b1 = (const float*)d_in[4];
  const float* W2 = (const float*)d_in[5];
  const float* b2 = (const float*)d_in[6];
  const float* Wc = (const float*)d_in[7];
  const float* bc = (const float*)d_in[8];
  float* y = (float*)d_out;

  // workspace carve
  char* p = (char*)d_ws;
  unsigned short* xb  = (unsigned short*)p; p += (size_t)kB * kD * 2;
  unsigned short* W1t = (unsigned short*)p; p += (size_t)kE * kH * kD * 2;
  unsigned short* W2t = (unsigned short*)p; p += (size_t)kE * kD * kH * 2;
  float* r   = (float*)p;                   p += (size_t)kB * kE * 4;
  float* out = (float*)p;                   p += (size_t)kB * kD * 4;
  unsigned short* h = (unsigned short*)p;
  const size_t base = (size_t)(p - (char*)d_ws);
  const size_t hOne = (size_t)kB * kH * 2;
  const bool pathA = ws_size >= base + (size_t)kE * hOne;  // all-expert h fits?

  k_convert_x<<<dim3(kB * kD / 8 / 256), dim3(256), 0, stream>>>(x, xb);
  k_routing<<<dim3(kB / 4), dim3(256), 0, stream>>>(x, Wr, br, r);
  // W1 [E][D][H] -> W1t [E][H][D] ; W2 [E][H][D] -> W2t [E][D][H]
  k_transpose_w<<<dim3(kH / 32, kD / 32, kE), dim3(32, 8), 0, stream>>>(W1, W1t, kD, kH);
  k_transpose_w<<<dim3(kD / 32, kH / 32, kE), dim3(32, 8), 0, stream>>>(W2, W2t, kH, kD);

  if (pathA) {
    k_gemm1<<<dim3(kB / 128, kH / 128, kE), dim3(256), 0, stream>>>(xb, W1t, b1, r, h, 0, hOne / 2);
    k_gemm2<0><<<dim3(kB / 128, kD / 128), dim3(256), 0, stream>>>(h, W2t, b2, r, out, 0, kE);
  } else {
    for (int e = 0; e < kE; ++e) {
      k_gemm1<<<dim3(kB / 128, kH / 128, 1), dim3(256), 0, stream>>>(xb, W1t, b1, r, h, e, 0);
      if (e == 0)
        k_gemm2<0><<<dim3(kB / 128, kD / 128), dim3(256), 0, stream>>>(h, W2t, b2, r, out, 0, 1);
      else
        k_gemm2<1><<<dim3(kB / 128, kD / 128), dim3(256), 0, stream>>>(h, W2t, b2, r, out, e, 1);
    }
  }
  k_final<<<dim3(kB / 4), dim3(256), 0, stream>>>(out, Wc, bc, y);
}

// Round 2
// 1125.598 us; speedup vs baseline: 1.6610x; 1.6610x over previous
//
#include <hip/hip_runtime.h>
#include <cstdint>
#include <cstddef>

using bf16x8 = __attribute__((ext_vector_type(8))) short;
using f32x4  = __attribute__((ext_vector_type(4))) float;

constexpr int kB = 8192;
constexpr int kD = 1024;
constexpr int kE = 8;
constexpr int kH = 4096;
constexpr int kC = 10;

__device__ __forceinline__ unsigned short f2bf(float f) {
  unsigned int u = __float_as_uint(f);
  u += 0x7FFFu + ((u >> 16) & 1u);   // round-to-nearest-even (finite inputs)
  return (unsigned short)(u >> 16);
}

#define GLD16(gptr, lptr)                                                      \
  __builtin_amdgcn_global_load_lds(                                            \
      (const __attribute__((address_space(1))) void*)(gptr),                   \
      (__attribute__((address_space(3))) void*)(lptr), 16, 0, 0)

// ---------------- convert x: f32 -> bf16, 8 elems/thread ----------------
__global__ __launch_bounds__(256) void k_convert_x(const float* __restrict__ x,
                                                   unsigned short* __restrict__ xb) {
  const long i = ((long)blockIdx.x * 256 + threadIdx.x) * 8;
  float4 a = *reinterpret_cast<const float4*>(x + i);
  float4 b = *reinterpret_cast<const float4*>(x + i + 4);
  bf16x8 o;
  o[0] = (short)f2bf(a.x); o[1] = (short)f2bf(a.y);
  o[2] = (short)f2bf(a.z); o[3] = (short)f2bf(a.w);
  o[4] = (short)f2bf(b.x); o[5] = (short)f2bf(b.y);
  o[6] = (short)f2bf(b.z); o[7] = (short)f2bf(b.w);
  *reinterpret_cast<bf16x8*>(xb + i) = o;
}

// ------------- transpose+convert W [E][K][N] f32 -> Wt [E][N][K] bf16 -------------
__global__ __launch_bounds__(256) void k_transpose_w(const float* __restrict__ W,
                                                     unsigned short* __restrict__ Wt,
                                                     int K, int N) {
  __shared__ unsigned short tile[32][33];
  const int e = blockIdx.z;
  const int n0 = blockIdx.x * 32, k0 = blockIdx.y * 32;
  const int tx = threadIdx.x, ty = threadIdx.y;  // (32,8)
  const float* Wb = W + (size_t)e * K * N;
  unsigned short* Wtb = Wt + (size_t)e * N * K;
#pragma unroll
  for (int j = 0; j < 32; j += 8)
    tile[ty + j][tx] = f2bf(Wb[(size_t)(k0 + ty + j) * N + n0 + tx]);
  __syncthreads();
#pragma unroll
  for (int j = 0; j < 32; j += 8)
    Wtb[(size_t)(n0 + ty + j) * K + k0 + tx] = tile[tx][ty + j];
}

// ---------------- routing: softmax(x @ Wr + br), one wave per row ----------------
__global__ __launch_bounds__(256) void k_routing(const float* __restrict__ x,
                                                 const float* __restrict__ Wr,
                                                 const float* __restrict__ br,
                                                 float* __restrict__ r) {
  const int w = threadIdx.x >> 6, l = threadIdx.x & 63;
  const int b = blockIdx.x * 4 + w;
  const float* xr = x + (size_t)b * kD;
  float acc[kE];
#pragma unroll
  for (int e = 0; e < kE; ++e) acc[e] = 0.f;
  for (int d = l; d < kD; d += 64) {
    const float xv = xr[d];
    const float* wrow = Wr + d * kE;
#pragma unroll
    for (int e = 0; e < kE; ++e) acc[e] += xv * wrow[e];
  }
#pragma unroll
  for (int e = 0; e < kE; ++e) {
#pragma unroll
    for (int s = 32; s > 0; s >>= 1) acc[e] += __shfl_xor(acc[e], s);
    acc[e] += br[e];
  }
  float mx = acc[0];
#pragma unroll
  for (int e = 1; e < kE; ++e) mx = fmaxf(mx, acc[e]);
  float sum = 0.f;
#pragma unroll
  for (int e = 0; e < kE; ++e) { acc[e] = expf(acc[e] - mx); sum += acc[e]; }
  const float inv = 1.f / sum;
  float val = 0.f;
#pragma unroll
  for (int e = 0; e < kE; ++e) if (l == e) val = acc[e] * inv;
  if (l < kE) r[(size_t)b * kE + l] = val;
}

// ---------------- zero-fill bf16 buffer, 8 elems/thread ----------------
__global__ __launch_bounds__(256) void k_zero(unsigned short* __restrict__ p) {
  const long i = ((long)blockIdx.x * 256 + threadIdx.x) * 8;
  *reinterpret_cast<bf16x8*>(p + i) = (bf16x8){0, 0, 0, 0, 0, 0, 0, 0};
}

// ------- V-build: Vt[e][c][h] = sum_d W2[e][h][d] * Wc[d][c], bf16, c<10 -------
__global__ __launch_bounds__(128) void k_vbuild(const float* __restrict__ W2,
                                                const float* __restrict__ Wc,
                                                unsigned short* __restrict__ Vt) {
  __shared__ float WcL[kD * kC];  // 40 KB
  for (int i = threadIdx.x; i < kD * kC; i += 128) WcL[i] = Wc[i];
  __syncthreads();
  const int gid = blockIdx.x * 128 + threadIdx.x;  // 0..32767 = e*4096 + h
  const int e = gid >> 12, hrow = gid & 4095;
  const float4* w2row = reinterpret_cast<const float4*>(W2 + (size_t)gid * kD);
  float acc[kC];
#pragma unroll
  for (int c = 0; c < kC; ++c) acc[c] = 0.f;
  for (int i = 0; i < kD / 4; ++i) {
    float4 w = w2row[i];
    const float* wc0 = WcL + (i * 4) * kC;
#pragma unroll
    for (int c = 0; c < kC; ++c)
      acc[c] += w.x * wc0[c] + w.y * wc0[kC + c] + w.z * wc0[2 * kC + c] +
                w.w * wc0[3 * kC + c];
  }
  unsigned short* vte = Vt + (size_t)e * 128 * kH;
#pragma unroll
  for (int c = 0; c < kC; ++c) vte[(size_t)c * kH + hrow] = f2bf(acc[c]);
}

// ------- u-build: u[e][c] = sum_d b2[e][d] * Wc[d][c] -------
__global__ __launch_bounds__(128) void k_ubuild(const float* __restrict__ b2,
                                                const float* __restrict__ Wc,
                                                float* __restrict__ u) {
  const int t = threadIdx.x;
  if (t >= kE * kC) return;
  const int e = t / kC, c = t % kC;
  float acc = 0.f;
  for (int d = 0; d < kD; ++d) acc += b2[e * kD + d] * Wc[d * kC + c];
  u[e * 16 + c] = acc;
}

// ------- 128x128 bf16 GEMM core, 2-phase double-buffered LDS -------
__device__ __forceinline__ void gemm_core_db(const unsigned short* __restrict__ A,
                                             const unsigned short* __restrict__ Bt,
                                             int K, unsigned short* As, unsigned short* Bs,
                                             int brow, int bcol, f32x4 acc[4][4]) {
  const int tid = threadIdx.x;
  const int w = tid >> 6, l = tid & 63;
  const int wr = w >> 1, wc = w & 1;
  const int srow = tid >> 2;        // 0..63, row within staging round
  const int scol = (tid & 3) * 8;   // k-offset of the 8-elem chunk
  const size_t arow0 = (size_t)(brow + srow) * K + scol;
  const size_t arow1 = (size_t)(brow + 64 + srow) * K + scol;
  const size_t brow0 = (size_t)(bcol + srow) * K + scol;
  const size_t brow1 = (size_t)(bcol + 64 + srow) * K + scol;
  unsigned short* const ldsA0 = As + (w * 64) * 8;  // wave-uniform LDS bases
  unsigned short* const ldsA1 = As + (256 + w * 64) * 8;
  unsigned short* const ldsB0 = Bs + (w * 64) * 8;
  unsigned short* const ldsB1 = Bs + (256 + w * 64) * 8;
  constexpr int BUF = 128 * 32;  // shorts per buffer

  // prologue: stage buf0 @ kt=0
  GLD16(A + arow0, ldsA0);
  GLD16(A + arow1, ldsA1);
  GLD16(Bt + brow0, ldsB0);
  GLD16(Bt + brow1, ldsB1);
  __syncthreads();  // vmcnt(0): buf0 valid

  int cur = 0;
  for (int kt = 32; kt <= K; kt += 32) {
    const int nxt = cur ^ 1;
    if (kt < K) {  // issue next-tile loads; they fly under this tile's MFMA
      GLD16(A + arow0 + kt, ldsA0 + nxt * BUF);
      GLD16(A + arow1 + kt, ldsA1 + nxt * BUF);
      GLD16(Bt + brow0 + kt, ldsB0 + nxt * BUF);
      GLD16(Bt + brow1 + kt, ldsB1 + nxt * BUF);
    }
    const unsigned short* cA = As + cur * BUF;
    const unsigned short* cB = Bs + cur * BUF;
    bf16x8 af[4], bfr[4];
#pragma unroll
    for (int m = 0; m < 4; ++m)
      af[m] = *reinterpret_cast<const bf16x8*>(cA + (wr * 64 + m * 16 + (l & 15)) * 32 + ((l >> 4) * 8));
#pragma unroll
    for (int n = 0; n < 4; ++n)
      bfr[n] = *reinterpret_cast<const bf16x8*>(cB + (wc * 64 + n * 16 + (l & 15)) * 32 + ((l >> 4) * 8));
#pragma unroll
    for (int m = 0; m < 4; ++m)
#pragma unroll
      for (int n = 0; n < 4; ++n)
        acc[m][n] = __builtin_amdgcn_mfma_f32_16x16x32_bf16(af[m], bfr[n], acc[m][n], 0, 0, 0);
    if (kt < K) __syncthreads();  // vmcnt(0)+lgkm(0): next buf staged, cur free
    cur = nxt;
  }
}

// ---------------- GEMM1: h' = r[:,e] * relu(x @ W1[e] + b1[e]) -> bf16 ----------------
__global__ __launch_bounds__(256) void k_gemm1(const unsigned short* __restrict__ xb,
                                               const unsigned short* __restrict__ W1t,
                                               const float* __restrict__ b1,
                                               const float* __restrict__ rr,
                                               unsigned short* __restrict__ h,
                                               int e0) {
  __shared__ __align__(16) unsigned short As[2 * 128 * 32];
  __shared__ __align__(16) unsigned short Bs[2 * 128 * 32];
  const int e = e0 + blockIdx.z;
  const int brow = blockIdx.x * 128, bcol = blockIdx.y * 128;
  f32x4 acc[4][4];
#pragma unroll
  for (int m = 0; m < 4; ++m)
#pragma unroll
    for (int n = 0; n < 4; ++n) acc[m][n] = (f32x4){0.f, 0.f, 0.f, 0.f};

  gemm_core_db(xb, W1t + (size_t)e * kH * kD, kD, As, Bs, brow, bcol, acc);

  const int l = threadIdx.x & 63, w = threadIdx.x >> 6;
  const int wr = w >> 1, wc = w & 1;
  unsigned short* hb = h + (size_t)blockIdx.z * kB * kH;
#pragma unroll
  for (int m = 0; m < 4; ++m) {
    const int r0 = brow + wr * 64 + m * 16 + ((l >> 4) * 4);
#pragma unroll
    for (int n = 0; n < 4; ++n) {
      const int col = bcol + wc * 64 + n * 16 + (l & 15);
      const float bias = b1[e * kH + col];
#pragma unroll
      for (int j = 0; j < 4; ++j) {
        const int row = r0 + j;
        float v = acc[m][n][j] + bias;
        v = fmaxf(v, 0.f) * rr[(size_t)row * kE + e];
        hb[(size_t)row * kH + col] = f2bf(v);
      }
    }
  }
}

// ------- skinny GEMM: part[e][b][c] = sum_k h'_e[b][k] * Vt[e][c][k] -------
__global__ __launch_bounds__(256) void k_skinny(const unsigned short* __restrict__ h,
                                                const unsigned short* __restrict__ Vt,
                                                float* __restrict__ part, int e0) {
  __shared__ __align__(16) unsigned short As[2 * 128 * 32];
  __shared__ __align__(16) unsigned short Bs[2 * 128 * 32];
  const int e = e0 + blockIdx.z;
  const int brow = blockIdx.x * 128;
  f32x4 acc[4][4];
#pragma unroll
  for (int m = 0; m < 4; ++m)
#pragma unroll
    for (int n = 0; n < 4; ++n) acc[m][n] = (f32x4){0.f, 0.f, 0.f, 0.f};

  gemm_core_db(h + (size_t)blockIdx.z * kB * kH, Vt + (size_t)e * 128 * kH, kH,
               As, Bs, brow, 0, acc);

  const int l = threadIdx.x & 63, w = threadIdx.x >> 6;
  const int wr = w >> 1, wc = w & 1;
  if (wc != 0) return;  // only cols 0..15 are real (n=0 frag of wc=0)
  float* pp = part + (size_t)e * kB * 16;
#pragma unroll
  for (int m = 0; m < 4; ++m) {
    const int r0 = brow + wr * 64 + m * 16 + ((l >> 4) * 4);
#pragma unroll
    for (int j = 0; j < 4; ++j)
      pp[(size_t)(r0 + j) * 16 + (l & 15)] = acc[m][0][j];
  }
}

// ------- combine: y[b][c] = sum_e part[e][b][c] + sum_e r[b][e]*u[e][c] + bc[c] -------
__global__ __launch_bounds__(256) void k_combine(const float* __restrict__ part,
                                                 const float* __restrict__ rr,
                                                 const float* __restrict__ u,
                                                 const float* __restrict__ bc,
                                                 float* __restrict__ y) {
  const int tid = threadIdx.x;
  const int rloc = tid >> 4, c = tid & 15;
  const int b = blockIdx.x * 16 + rloc;
  if (c >= kC) return;
  float acc = bc[c];
#pragma unroll
  for (int e = 0; e < kE; ++e) {
    acc += part[(size_t)e * kB * 16 + (size_t)b * 16 + c];
    acc += rr[(size_t)b * kE + e] * u[e * 16 + c];
  }
  y[(size_t)b * kC + c] = acc;
}

extern "C" void kernel_launch(void* const* d_in, const int* in_sizes, int n_in,
                              void* d_out, int out_size, void* d_ws, size_t ws_size,
                              hipStream_t stream) {
  (void)in_sizes; (void)n_in; (void)out_size;
  const float* x  = (const float*)d_in[0];
  const float* Wr = (const float*)d_in[1];
  const float* br = (const float*)d_in[2];
  const float* W1 = (const float*)d_in[3];
  const float* b1 = (const float*)d_in[4];
  const float* W2 = (const float*)d_in[5];
  const float* b2 = (const float*)d_in[6];
  const float* Wc = (const float*)d_in[7];
  const float* bc = (const float*)d_in[8];
  float* y = (float*)d_out;

  // workspace carve
  char* p = (char*)d_ws;
  unsigned short* xb  = (unsigned short*)p; p += (size_t)kB * kD * 2;          // 16 MB
  unsigned short* W1t = (unsigned short*)p; p += (size_t)kE * kH * kD * 2;     // 64 MB
  unsigned short* Vt  = (unsigned short*)p; p += (size_t)kE * 128 * kH * 2;    // 8 MB
  float* r    = (float*)p;                  p += (size_t)kB * kE * 4;          // 256 KB
  float* u    = (float*)p;                  p += (size_t)kE * 16 * 4;          // 512 B
  float* part = (float*)p;                  p += (size_t)kE * kB * 16 * 4;     // 4 MB
  unsigned short* h = (unsigned short*)p;
  const size_t base = (size_t)(p - (char*)d_ws);
  const size_t hOne = (size_t)kB * kH * 2;  // 64 MB per expert
  int ne_g = 1;
  for (int g : {8, 4, 2}) {
    if (ws_size >= base + (size_t)g * hOne) { ne_g = g; break; }
  }

  k_convert_x<<<dim3(kB * kD / 8 / 256), dim3(256), 0, stream>>>(x, xb);
  k_routing<<<dim3(kB / 4), dim3(256), 0, stream>>>(x, Wr, br, r);
  // W1 [E][D][H] -> W1t [E][H][D]
  k_transpose_w<<<dim3(kH / 32, kD / 32, kE), dim3(32, 8), 0, stream>>>(W1, W1t, kD, kH);
  // Vt: zero pad rows, then fill rows c<10
  k_zero<<<dim3((kE * 128 * kH / 8) / 256), dim3(256), 0, stream>>>(Vt);
  k_vbuild<<<dim3(kE * kH / 128), dim3(128), 0, stream>>>(W2, Wc, Vt);
  k_ubuild<<<dim3(1), dim3(128), 0, stream>>>(b2, Wc, u);

  for (int g0 = 0; g0 < kE; g0 += ne_g) {
    k_gemm1<<<dim3(kB / 128, kH / 128, ne_g), dim3(256), 0, stream>>>(xb, W1t, b1, r, h, g0);
    k_skinny<<<dim3(kB / 128, 1, ne_g), dim3(256), 0, stream>>>(h, Vt, part, g0);
  }
  k_combine<<<dim3(kB / 16), dim3(256), 0, stream>>>(part, r, u, bc, y);
}

// Round 3
// 759.709 us; speedup vs baseline: 2.4609x; 1.4816x over previous
//
#include <hip/hip_runtime.h>
#include <cstdint>
#include <cstddef>

using bf16x8 = __attribute__((ext_vector_type(8))) short;
using f32x4  = __attribute__((ext_vector_type(4))) float;

constexpr int kB = 8192;
constexpr int kD = 1024;
constexpr int kE = 8;
constexpr int kH = 4096;
constexpr int kC = 10;

__device__ __forceinline__ unsigned short f2bf(float f) {
  unsigned int u = __float_as_uint(f);
  u += 0x7FFFu + ((u >> 16) & 1u);   // round-to-nearest-even (finite inputs)
  return (unsigned short)(u >> 16);
}

#define GLD16(gptr, lptr)                                                      \
  __builtin_amdgcn_global_load_lds(                                            \
      (const __attribute__((address_space(1))) void*)(gptr),                   \
      (__attribute__((address_space(3))) void*)(lptr), 16, 0, 0)

// raw barrier with lgkm drain + compiler fences (no vmcnt drain!)
#define SBAR()                                                                 \
  do {                                                                         \
    asm volatile("s_waitcnt lgkmcnt(0)" ::: "memory");                         \
    __builtin_amdgcn_s_barrier();                                              \
    asm volatile("" ::: "memory");                                             \
    __builtin_amdgcn_sched_barrier(0);                                         \
  } while (0)

// logical (row, jchunk) -> physical byte in an 8 KB staged tile [rows][32k bf16]
// superrow (2-row / 128 B) XOR swizzle: spreads reads across 8 x 16B slots.
__device__ __forceinline__ int lbyte(int row, int j) {
  const int s = row >> 1;
  const int jp = (((row & 1) << 2) | j) ^ (s & 7);
  return s * 128 + jp * 16;
}

// ---------------- convert x: f32 -> bf16, 8 elems/thread ----------------
__global__ __launch_bounds__(256) void k_convert_x(const float* __restrict__ x,
                                                   unsigned short* __restrict__ xb) {
  const long i = ((long)blockIdx.x * 256 + threadIdx.x) * 8;
  float4 a = *reinterpret_cast<const float4*>(x + i);
  float4 b = *reinterpret_cast<const float4*>(x + i + 4);
  bf16x8 o;
  o[0] = (short)f2bf(a.x); o[1] = (short)f2bf(a.y);
  o[2] = (short)f2bf(a.z); o[3] = (short)f2bf(a.w);
  o[4] = (short)f2bf(b.x); o[5] = (short)f2bf(b.y);
  o[6] = (short)f2bf(b.z); o[7] = (short)f2bf(b.w);
  *reinterpret_cast<bf16x8*>(xb + i) = o;
}

// ------------- transpose+convert W1 [E][D][H] f32 -> W1t [E][H][D] bf16 -------------
__global__ __launch_bounds__(256) void k_transpose_w(const float* __restrict__ W,
                                                     unsigned short* __restrict__ Wt,
                                                     int K, int N) {
  __shared__ unsigned short tile[32][33];
  const int e = blockIdx.z;
  const int n0 = blockIdx.x * 32, k0 = blockIdx.y * 32;
  const int tx = threadIdx.x, ty = threadIdx.y;  // (32,8)
  const float* Wb = W + (size_t)e * K * N;
  unsigned short* Wtb = Wt + (size_t)e * N * K;
#pragma unroll
  for (int j = 0; j < 32; j += 8)
    tile[ty + j][tx] = f2bf(Wb[(size_t)(k0 + ty + j) * N + n0 + tx]);
  __syncthreads();
#pragma unroll
  for (int j = 0; j < 32; j += 8)
    Wtb[(size_t)(n0 + ty + j) * K + k0 + tx] = tile[tx][ty + j];
}

// ---------------- routing: softmax(x @ Wr + br), one wave per row ----------------
__global__ __launch_bounds__(256) void k_routing(const float* __restrict__ x,
                                                 const float* __restrict__ Wr,
                                                 const float* __restrict__ br,
                                                 float* __restrict__ r) {
  const int w = threadIdx.x >> 6, l = threadIdx.x & 63;
  const int b = blockIdx.x * 4 + w;
  const float* xr = x + (size_t)b * kD;
  float acc[kE];
#pragma unroll
  for (int e = 0; e < kE; ++e) acc[e] = 0.f;
  for (int d = l; d < kD; d += 64) {
    const float xv = xr[d];
    const float* wrow = Wr + d * kE;
#pragma unroll
    for (int e = 0; e < kE; ++e) acc[e] += xv * wrow[e];
  }
#pragma unroll
  for (int e = 0; e < kE; ++e) {
#pragma unroll
    for (int s = 32; s > 0; s >>= 1) acc[e] += __shfl_xor(acc[e], s);
    acc[e] += br[e];
  }
  float mx = acc[0];
#pragma unroll
  for (int e = 1; e < kE; ++e) mx = fmaxf(mx, acc[e]);
  float sum = 0.f;
#pragma unroll
  for (int e = 0; e < kE; ++e) { acc[e] = expf(acc[e] - mx); sum += acc[e]; }
  const float inv = 1.f / sum;
  float val = 0.f;
#pragma unroll
  for (int e = 0; e < kE; ++e) if (l == e) val = acc[e] * inv;
  if (l < kE) r[(size_t)b * kE + l] = val;
}

// ------- V-build: Vt[e][c][h] = sum_d W2[e][h][d]*Wc[d][c]; rows c>=10 zeroed -------
__global__ __launch_bounds__(128) void k_vbuild(const float* __restrict__ W2,
                                                const float* __restrict__ Wc,
                                                unsigned short* __restrict__ Vt) {
  __shared__ float WcL[kD * kC];  // 40 KB
  for (int i = threadIdx.x; i < kD * kC; i += 128) WcL[i] = Wc[i];
  __syncthreads();
  const int gid = blockIdx.x * 128 + threadIdx.x;  // e*4096 + h
  const int e = gid >> 12, hrow = gid & 4095;
  const float4* w2row = reinterpret_cast<const float4*>(W2 + (size_t)gid * kD);
  float acc[kC];
#pragma unroll
  for (int c = 0; c < kC; ++c) acc[c] = 0.f;
  for (int i = 0; i < kD / 4; ++i) {
    float4 w = w2row[i];
    const float* wc0 = WcL + (i * 4) * kC;
#pragma unroll
    for (int c = 0; c < kC; ++c)
      acc[c] += w.x * wc0[c] + w.y * wc0[kC + c] + w.z * wc0[2 * kC + c] +
                w.w * wc0[3 * kC + c];
  }
  unsigned short* vte = Vt + (size_t)e * 16 * kH;
#pragma unroll
  for (int c = 0; c < kC; ++c) vte[(size_t)c * kH + hrow] = f2bf(acc[c]);
#pragma unroll
  for (int c = kC; c < 16; ++c) vte[(size_t)c * kH + hrow] = 0;
}

// ------- u-build: u[e][c] = sum_d b2[e][d] * Wc[d][c] -------
__global__ __launch_bounds__(128) void k_ubuild(const float* __restrict__ b2,
                                                const float* __restrict__ Wc,
                                                float* __restrict__ u) {
  const int t = threadIdx.x;
  if (t >= kE * kC) return;
  const int e = t / kC, c = t % kC;
  float acc = 0.f;
  for (int d = 0; d < kD; ++d) acc += b2[e * kD + d] * Wc[d * kC + c];
  u[e * 16 + c] = acc;
}

__global__ __launch_bounds__(256) void k_zero_f32(float* __restrict__ p) {
  p[(size_t)blockIdx.x * 256 + threadIdx.x] = 0.f;
}

// ============ fused: part[b][c] += r[b,e] * sum_h relu(x@W1[e]+b1)[b,h] * Vt[e][c][h] ============
// 128x128 tile, BK=32, tri-buffered LDS (48 KB), counted vmcnt, swizzled reads.
__global__ __launch_bounds__(256, 3) void k_moe_fused(
    const unsigned short* __restrict__ xb,   // [B][D] bf16
    const unsigned short* __restrict__ W1t,  // [E][H][D] bf16
    const float* __restrict__ b1,            // [E][H]
    const unsigned short* __restrict__ Vt,   // [E][16][H] bf16
    const float* __restrict__ rr,            // [B][E]
    float* __restrict__ part) {              // [B][16] f32 (atomic accum)
  __shared__ __align__(16) char smem[49152];  // 3 bufs x (A 8KB + B 8KB)
  constexpr int K = kD, BK = 32, NT = K / BK;  // 32 tiles

  const int e = blockIdx.z;
  const int bx = (blockIdx.x & 7) * 8 + (blockIdx.x >> 3);  // bijective XCD swizzle
  const int brow = bx * 128, bcol = blockIdx.y * 128;
  const unsigned short* const A = xb;
  const unsigned short* const Bt = W1t + (size_t)e * kH * kD;

  const int tid = threadIdx.x;
  const int l = tid & 63, w = tid >> 6;
  const int wr = w >> 1, wc = w & 1;
  const int fr = l & 15, jg = l >> 4;

  // --- staging address precompute (inverse-swizzled global source, linear LDS dest) ---
  const int jsup = (tid & 7) ^ ((tid >> 3) & 7);
  const int row0 = (((tid >> 3) << 1) | (jsup >> 2));  // 0..63
  const int sj = jsup & 3;
  const size_t gA0 = (size_t)(brow + row0) * K + sj * 8;
  const size_t gA1 = (size_t)(brow + 64 + row0) * K + sj * 8;
  const size_t gB0 = (size_t)(bcol + row0) * K + sj * 8;
  const size_t gB1 = (size_t)(bcol + 64 + row0) * K + sj * 8;
  const int wb0 = w * 1024, wb1 = 4096 + w * 1024;  // wave-uniform LDS dest bases

#define STAGE(bufbyte, kt)                                                     \
  do {                                                                         \
    GLD16(A + gA0 + (size_t)(kt) * BK, smem + (bufbyte) + wb0);                \
    GLD16(A + gA1 + (size_t)(kt) * BK, smem + (bufbyte) + wb1);                \
    GLD16(Bt + gB0 + (size_t)(kt) * BK, smem + (bufbyte) + 8192 + wb0);        \
    GLD16(Bt + gB1 + (size_t)(kt) * BK, smem + (bufbyte) + 8192 + wb1);        \
  } while (0)

  // --- fragment read offsets (loop-invariant) ---
  int offA[4], offB[4];
#pragma unroll
  for (int m = 0; m < 4; ++m) offA[m] = lbyte(wr * 64 + m * 16 + fr, jg);
#pragma unroll
  for (int n = 0; n < 4; ++n) offB[n] = lbyte(wc * 64 + n * 16 + fr, jg);

  f32x4 acc[4][4];
#pragma unroll
  for (int m = 0; m < 4; ++m)
#pragma unroll
    for (int n = 0; n < 4; ++n) acc[m][n] = (f32x4){0.f, 0.f, 0.f, 0.f};

  // --- prologue: tiles 0,1 in flight; wait tile 0 only (vmcnt 4 = tile 1 stays out) ---
  STAGE(0, 0);
  STAGE(16384, 1);
  asm volatile("s_waitcnt vmcnt(4)" ::: "memory");
  __builtin_amdgcn_s_barrier();
  asm volatile("" ::: "memory");
  __builtin_amdgcn_sched_barrier(0);

  int bufb = 0;
  for (int t = 0; t < NT; ++t) {
    int nxt = bufb + 16384; if (nxt == 49152) nxt = 0;
    int n2 = nxt + 16384;  if (n2 == 49152) n2 = 0;
    if (t + 2 < NT) STAGE(n2, t + 2);  // DMA flies under this tile's compute

    const char* const Ab = smem + bufb;
    const char* const Bb = smem + bufb + 8192;
    bf16x8 av[4], bv[4];
#pragma unroll
    for (int m = 0; m < 4; ++m) av[m] = *reinterpret_cast<const bf16x8*>(Ab + offA[m]);
#pragma unroll
    for (int n = 0; n < 4; ++n) bv[n] = *reinterpret_cast<const bf16x8*>(Bb + offB[n]);
    __builtin_amdgcn_s_setprio(1);
#pragma unroll
    for (int m = 0; m < 4; ++m)
#pragma unroll
      for (int n = 0; n < 4; ++n)
        acc[m][n] = __builtin_amdgcn_mfma_f32_16x16x32_bf16(av[m], bv[n], acc[m][n], 0, 0, 0);
    __builtin_amdgcn_s_setprio(0);

    if (t < NT - 1) {
      if (t + 2 < NT) asm volatile("s_waitcnt vmcnt(4)" ::: "memory");  // next tile landed
      else            asm volatile("s_waitcnt vmcnt(0)" ::: "memory");  // tail drain
      SBAR();
    }
    bufb = nxt;
  }
#undef STAGE

  // ===== epilogue: g = relu(acc + b1) -> LDS (bf16, swizzled); then g x V^T; atomics =====
  SBAR();  // all waves done reading staged bufs; smem now reused for g [128][128] bf16

  float b1v[4];
#pragma unroll
  for (int n = 0; n < 4; ++n)
    b1v[n] = b1[(size_t)e * kH + bcol + wc * 64 + n * 16 + fr];

#pragma unroll
  for (int m = 0; m < 4; ++m) {
#pragma unroll
    for (int n = 0; n < 4; ++n) {
      const int colh = wc * 64 + n * 16 + fr;
#pragma unroll
      for (int j = 0; j < 4; ++j) {
        const int row = wr * 64 + m * 16 + (jg << 2) + j;
        const float v = fmaxf(acc[m][n][j] + b1v[n], 0.f);
        *reinterpret_cast<unsigned short*>(
            smem + row * 256 + ((colh * 2) ^ ((row & 7) << 4))) = f2bf(v);
      }
    }
  }
  SBAR();

  // small GEMM: part-rows (2w+f)*16, contract k = 128 hcols (4 x K32)
  const unsigned short* const VtE = Vt + (size_t)e * 16 * kH;
  bf16x8 gvk[4];
#pragma unroll
  for (int kk = 0; kk < 4; ++kk)
    gvk[kk] = *reinterpret_cast<const bf16x8*>(VtE + (size_t)fr * kH + bcol + kk * 32 + jg * 8);

  f32x4 pc[2];
  pc[0] = (f32x4){0.f, 0.f, 0.f, 0.f};
  pc[1] = (f32x4){0.f, 0.f, 0.f, 0.f};
#pragma unroll
  for (int f = 0; f < 2; ++f) {
    const int rowl = (2 * w + f) * 16 + fr;
#pragma unroll
    for (int kk = 0; kk < 4; ++kk) {
      bf16x8 ga = *reinterpret_cast<const bf16x8*>(
          smem + rowl * 256 + ((kk * 64 + jg * 16) ^ ((rowl & 7) << 4)));
      pc[f] = __builtin_amdgcn_mfma_f32_16x16x32_bf16(ga, gvk[kk], pc[f], 0, 0, 0);
    }
  }

#pragma unroll
  for (int f = 0; f < 2; ++f) {
    const int rowg = brow + (2 * w + f) * 16 + (jg << 2);
#pragma unroll
    for (int j = 0; j < 4; ++j) {
      const float val = pc[f][j] * rr[(size_t)(rowg + j) * kE + e];
      atomicAdd(&part[(size_t)(rowg + j) * 16 + fr], val);
    }
  }
}

// ------- combine: y[b][c] = part[b][c] + sum_e r[b][e]*u[e][c] + bc[c] -------
__global__ __launch_bounds__(256) void k_combine(const float* __restrict__ part,
                                                 const float* __restrict__ rr,
                                                 const float* __restrict__ u,
                                                 const float* __restrict__ bc,
                                                 float* __restrict__ y) {
  const int tid = threadIdx.x;
  const int rloc = tid >> 4, c = tid & 15;
  const int b = blockIdx.x * 16 + rloc;
  if (c >= kC) return;
  float acc = part[(size_t)b * 16 + c] + bc[c];
#pragma unroll
  for (int e = 0; e < kE; ++e) acc += rr[(size_t)b * kE + e] * u[e * 16 + c];
  y[(size_t)b * kC + c] = acc;
}

extern "C" void kernel_launch(void* const* d_in, const int* in_sizes, int n_in,
                              void* d_out, int out_size, void* d_ws, size_t ws_size,
                              hipStream_t stream) {
  (void)in_sizes; (void)n_in; (void)out_size; (void)ws_size;
  const float* x  = (const float*)d_in[0];
  const float* Wr = (const float*)d_in[1];
  const float* br = (const float*)d_in[2];
  const float* W1 = (const float*)d_in[3];
  const float* b1 = (const float*)d_in[4];
  const float* W2 = (const float*)d_in[5];
  const float* b2 = (const float*)d_in[6];
  const float* Wc = (const float*)d_in[7];
  const float* bc = (const float*)d_in[8];
  float* y = (float*)d_out;

  // workspace carve (~82 MB)
  char* p = (char*)d_ws;
  unsigned short* xb  = (unsigned short*)p; p += (size_t)kB * kD * 2;        // 16 MB
  unsigned short* W1t = (unsigned short*)p; p += (size_t)kE * kH * kD * 2;   // 64 MB
  unsigned short* Vt  = (unsigned short*)p; p += (size_t)kE * 16 * kH * 2;   // 1 MB
  float* r    = (float*)p;                  p += (size_t)kB * kE * 4;        // 256 KB
  float* u    = (float*)p;                  p += (size_t)kE * 16 * 4;        // 512 B
  float* part = (float*)p;                  p += (size_t)kB * 16 * 4;        // 512 KB

  k_convert_x<<<dim3(kB * kD / 8 / 256), dim3(256), 0, stream>>>(x, xb);
  k_routing<<<dim3(kB / 4), dim3(256), 0, stream>>>(x, Wr, br, r);
  k_transpose_w<<<dim3(kH / 32, kD / 32, kE), dim3(32, 8), 0, stream>>>(W1, W1t, kD, kH);
  k_vbuild<<<dim3(kE * kH / 128), dim3(128), 0, stream>>>(W2, Wc, Vt);
  k_ubuild<<<dim3(1), dim3(128), 0, stream>>>(b2, Wc, u);
  k_zero_f32<<<dim3(kB * 16 / 256), dim3(256), 0, stream>>>(part);

  k_moe_fused<<<dim3(kB / 128, kH / 128, kE), dim3(256), 0, stream>>>(
      xb, W1t, b1, Vt, r, part);

  k_combine<<<dim3(kB / 16), dim3(256), 0, stream>>>(part, r, u, bc, y);
}

// Round 4
// 697.823 us; speedup vs baseline: 2.6792x; 1.0887x over previous
//
#include <hip/hip_runtime.h>
#include <cstdint>
#include <cstddef>

using bf16x8 = __attribute__((ext_vector_type(8))) short;
using f32x4  = __attribute__((ext_vector_type(4))) float;

constexpr int kB = 8192;
constexpr int kD = 1024;
constexpr int kE = 8;
constexpr int kH = 4096;
constexpr int kC = 10;

__device__ __forceinline__ unsigned short f2bf(float f) {
  unsigned int u = __float_as_uint(f);
  u += 0x7FFFu + ((u >> 16) & 1u);   // round-to-nearest-even (finite inputs)
  return (unsigned short)(u >> 16);
}

#define GLD16(gptr, lptr)                                                      \
  __builtin_amdgcn_global_load_lds(                                            \
      (const __attribute__((address_space(1))) void*)(gptr),                   \
      (__attribute__((address_space(3))) void*)(lptr), 16, 0, 0)

// ---------------- convert x: f32 -> bf16, 8 elems/thread ----------------
__global__ __launch_bounds__(256) void k_convert_x(const float* __restrict__ x,
                                                   unsigned short* __restrict__ xb) {
  const long i = ((long)blockIdx.x * 256 + threadIdx.x) * 8;
  float4 a = *reinterpret_cast<const float4*>(x + i);
  float4 b = *reinterpret_cast<const float4*>(x + i + 4);
  bf16x8 o;
  o[0] = (short)f2bf(a.x); o[1] = (short)f2bf(a.y);
  o[2] = (short)f2bf(a.z); o[3] = (short)f2bf(a.w);
  o[4] = (short)f2bf(b.x); o[5] = (short)f2bf(b.y);
  o[6] = (short)f2bf(b.z); o[7] = (short)f2bf(b.w);
  *reinterpret_cast<bf16x8*>(xb + i) = o;
}

// ------------- transpose+convert W1 [E][D][H] f32 -> W1t [E][H][D] bf16 -------------
__global__ __launch_bounds__(256) void k_transpose_w(const float* __restrict__ W,
                                                     unsigned short* __restrict__ Wt,
                                                     int K, int N) {
  __shared__ unsigned short tile[32][33];
  const int e = blockIdx.z;
  const int n0 = blockIdx.x * 32, k0 = blockIdx.y * 32;
  const int tx = threadIdx.x, ty = threadIdx.y;  // (32,8)
  const float* Wb = W + (size_t)e * K * N;
  unsigned short* Wtb = Wt + (size_t)e * N * K;
#pragma unroll
  for (int j = 0; j < 32; j += 8)
    tile[ty + j][tx] = f2bf(Wb[(size_t)(k0 + ty + j) * N + n0 + tx]);
  __syncthreads();
#pragma unroll
  for (int j = 0; j < 32; j += 8)
    Wtb[(size_t)(n0 + ty + j) * K + k0 + tx] = tile[tx][ty + j];
}

// ---------------- routing: softmax(x @ Wr + br), one wave per row ----------------
__global__ __launch_bounds__(256) void k_routing(const float* __restrict__ x,
                                                 const float* __restrict__ Wr,
                                                 const float* __restrict__ br,
                                                 float* __restrict__ r) {
  const int w = threadIdx.x >> 6, l = threadIdx.x & 63;
  const int b = blockIdx.x * 4 + w;
  const float* xr = x + (size_t)b * kD;
  float acc[kE];
#pragma unroll
  for (int e = 0; e < kE; ++e) acc[e] = 0.f;
  for (int d = l; d < kD; d += 64) {
    const float xv = xr[d];
    const float* wrow = Wr + d * kE;
#pragma unroll
    for (int e = 0; e < kE; ++e) acc[e] += xv * wrow[e];
  }
#pragma unroll
  for (int e = 0; e < kE; ++e) {
#pragma unroll
    for (int s = 32; s > 0; s >>= 1) acc[e] += __shfl_xor(acc[e], s);
    acc[e] += br[e];
  }
  float mx = acc[0];
#pragma unroll
  for (int e = 1; e < kE; ++e) mx = fmaxf(mx, acc[e]);
  float sum = 0.f;
#pragma unroll
  for (int e = 0; e < kE; ++e) { acc[e] = expf(acc[e] - mx); sum += acc[e]; }
  const float inv = 1.f / sum;
  float val = 0.f;
#pragma unroll
  for (int e = 0; e < kE; ++e) if (l == e) val = acc[e] * inv;
  if (l < kE) r[(size_t)b * kE + l] = val;
}

// ------- V-build: Vt[e][c][h] = sum_d W2[e][h][d]*Wc[d][c]; rows c>=10 zeroed -------
__global__ __launch_bounds__(128) void k_vbuild(const float* __restrict__ W2,
                                                const float* __restrict__ Wc,
                                                unsigned short* __restrict__ Vt) {
  __shared__ float WcL[kD * kC];  // 40 KB
  for (int i = threadIdx.x; i < kD * kC; i += 128) WcL[i] = Wc[i];
  __syncthreads();
  const int gid = blockIdx.x * 128 + threadIdx.x;  // e*4096 + h
  const int e = gid >> 12, hrow = gid & 4095;
  const float4* w2row = reinterpret_cast<const float4*>(W2 + (size_t)gid * kD);
  float acc[kC];
#pragma unroll
  for (int c = 0; c < kC; ++c) acc[c] = 0.f;
  for (int i = 0; i < kD / 4; ++i) {
    float4 w = w2row[i];
    const float* wc0 = WcL + (i * 4) * kC;
#pragma unroll
    for (int c = 0; c < kC; ++c)
      acc[c] += w.x * wc0[c] + w.y * wc0[kC + c] + w.z * wc0[2 * kC + c] +
                w.w * wc0[3 * kC + c];
  }
  unsigned short* vte = Vt + (size_t)e * 16 * kH;
#pragma unroll
  for (int c = 0; c < kC; ++c) vte[(size_t)c * kH + hrow] = f2bf(acc[c]);
#pragma unroll
  for (int c = kC; c < 16; ++c) vte[(size_t)c * kH + hrow] = 0;
}

// ------- u-build: u[e][c] = sum_d b2[e][d] * Wc[d][c] -------
__global__ __launch_bounds__(128) void k_ubuild(const float* __restrict__ b2,
                                                const float* __restrict__ Wc,
                                                float* __restrict__ u) {
  const int t = threadIdx.x;
  if (t >= kE * kC) return;
  const int e = t / kC, c = t % kC;
  float acc = 0.f;
  for (int d = 0; d < kD; ++d) acc += b2[e * kD + d] * Wc[d * kC + c];
  u[e * 16 + c] = acc;
}

__global__ __launch_bounds__(256) void k_zero_f32(float* __restrict__ p) {
  p[(size_t)blockIdx.x * 256 + threadIdx.x] = 0.f;
}

// ============================================================================
// fused 256x256 8-phase GEMM1 + V-contraction
//   part[b][c] += r[b,e] * sum_h relu(x@W1[e]+b1[e])[b,h] * Vt[e][c][h]
// 8 waves (2Mx4N), BK=64, 2 K-tile LDS buffers (128 KB), counted vmcnt(4),
// XOR-swizzled LDS reads (inverse swizzle on global source), setprio on MFMA.
// ============================================================================
__global__ __launch_bounds__(512, 2) void k_moe_fused256(
    const unsigned short* __restrict__ xb,   // [B][D] bf16
    const unsigned short* __restrict__ W1t,  // [E][H][D] bf16
    const float* __restrict__ b1,            // [E][H]
    const unsigned short* __restrict__ Vt,   // [E][16][H] bf16
    const float* __restrict__ rr,            // [B][E]
    float* __restrict__ part) {              // [B][16] f32 (atomic accum)
  __shared__ __align__(16) char smem[131072];
  constexpr int K = kD;          // 1024
  constexpr int NIT = K / 128;   // 8 iterations, 2 K-tiles (BK=64) each

  const int e = blockIdx.z;
  const int bx = (blockIdx.x & 7) * 4 + (blockIdx.x >> 3);  // bijective XCD swizzle (32%8==0)
  const int brow = bx * 256, bcol = blockIdx.y * 256;
  const unsigned short* const At = xb;
  const unsigned short* const Bt = W1t + (size_t)e * kH * kD;

  const int tid = threadIdx.x;
  const int w = tid >> 6, l = tid & 63;
  const int wr = w >> 2, wc = w & 3;       // wave grid 2M x 4N
  const int fr = l & 15, jg = l >> 4;      // fragment row / k-chunk group

  // fragment-read swizzled chunk offsets (row&7 == fr&7 since all row bases %16==0)
  int ck[2];
#pragma unroll
  for (int k = 0; k < 2; ++k) ck[k] = (((k * 4 + jg) ^ (fr & 7)) << 4);
  const int abase = wr * 16384;                 // + buf*65536           (A region)
  const int bbase = 32768 + (wc >> 1) * 16384;  // + buf*65536           (B region)
  const int brow0 = (wc & 1) * 64;              // B row base within half

  // staging: linear LDS dest, inverse-swizzled global source (rule 21)
  const int p0 = w * 64 + l;            // phys 16B chunk within an 8KB round
  const int rp = p0 >> 3;               // row 0..63 (round 0); +64 for round 1
  const int cs = (p0 & 7) ^ (rp & 7);   // logical chunk (same both rounds)
  const size_t aofs = (size_t)(brow + rp) * K + cs * 8;
  const size_t bofs = (size_t)(bcol + rp) * K + cs * 8;
  const int ldst = w * 1024;            // wave-uniform LDS dest offset

#define STG_A(buf, ht, kt)                                                     \
  do {                                                                         \
    GLD16(At + aofs + (size_t)(ht) * 131072 + (size_t)(kt) * 64,               \
          smem + (buf) * 65536 + (ht) * 16384 + ldst);                         \
    GLD16(At + aofs + (size_t)(ht) * 131072 + 65536 + (size_t)(kt) * 64,       \
          smem + (buf) * 65536 + (ht) * 16384 + 8192 + ldst);                  \
  } while (0)
#define STG_B(buf, ht, kt)                                                     \
  do {                                                                         \
    GLD16(Bt + bofs + (size_t)(ht) * 131072 + (size_t)(kt) * 64,               \
          smem + (buf) * 65536 + 32768 + (ht) * 16384 + ldst);                 \
    GLD16(Bt + bofs + (size_t)(ht) * 131072 + 65536 + (size_t)(kt) * 64,       \
          smem + (buf) * 65536 + 32768 + (ht) * 16384 + 8192 + ldst);          \
  } while (0)

#define READ_A(buf, mp)                                                        \
  do {                                                                         \
    _Pragma("unroll") for (int mm = 0; mm < 2; ++mm)                           \
    _Pragma("unroll") for (int k = 0; k < 2; ++k)                              \
      aq[mm][k] = *reinterpret_cast<const bf16x8*>(                            \
          smem + (buf) * 65536 + abase + (((mp) * 2 + mm) * 16 + fr) * 128 + ck[k]); \
  } while (0)
#define READ_B(buf)                                                            \
  do {                                                                         \
    _Pragma("unroll") for (int n = 0; n < 4; ++n)                              \
    _Pragma("unroll") for (int k = 0; k < 2; ++k)                              \
      bq[n][k] = *reinterpret_cast<const bf16x8*>(                             \
          smem + (buf) * 65536 + bbase + (brow0 + n * 16 + fr) * 128 + ck[k]); \
  } while (0)
#define MFMA16(mp)                                                             \
  do {                                                                         \
    __builtin_amdgcn_s_setprio(1);                                             \
    _Pragma("unroll") for (int mm = 0; mm < 2; ++mm)                           \
    _Pragma("unroll") for (int n = 0; n < 4; ++n)                              \
    _Pragma("unroll") for (int k = 0; k < 2; ++k)                              \
      acc[(mp) * 2 + mm][n] = __builtin_amdgcn_mfma_f32_16x16x32_bf16(         \
          aq[mm][k], bq[n][k], acc[(mp) * 2 + mm][n], 0, 0, 0);                \
    __builtin_amdgcn_s_setprio(0);                                             \
  } while (0)
#define BARW() asm volatile("s_barrier\ns_waitcnt lgkmcnt(0)" ::: "memory")
#define BARP() asm volatile("s_barrier" ::: "memory")

  bf16x8 aq[2][2], bq[4][2];
  f32x4 acc[8][4];
#pragma unroll
  for (int m = 0; m < 8; ++m)
#pragma unroll
    for (int n = 0; n < 4; ++n) acc[m][n] = (f32x4){0.f, 0.f, 0.f, 0.f};

  // prologue: X=buf0 gets KT0 (full), Y=buf1 gets KT1's B halves; Y.A comes in ph1/ph2
  STG_A(0, 0, 0); STG_A(0, 1, 0); STG_B(0, 0, 0); STG_B(0, 1, 0);
  STG_B(1, 0, 1); STG_B(1, 1, 1);
  asm volatile("s_waitcnt vmcnt(4)" ::: "memory");  // KT0 landed; Y.B (4) in flight
  BARP();

  for (int i = 0; i < NIT; ++i) {
    const bool g = (i < NIT - 1);
    const int kx = 2 * i + 2, ky = 2 * i + 3;
    // ---- ph1: X m-pair0; stage Y.A0 (KT 2i+1) [Y.A free since prev ph8] ----
    READ_A(0, 0); READ_B(0);
    STG_A(1, 0, 2 * i + 1);
    BARW(); MFMA16(0); BARP();
    // ---- ph2: X m-pair1; stage Y.A1, X'.B0 [X.B free after ph1] ----
    READ_A(0, 1);
    STG_A(1, 1, 2 * i + 1);
    if (g) STG_B(0, 0, kx);
    BARW(); MFMA16(1); BARP();
    // ---- ph3: X m-pair2; stage X'.B1 ----
    READ_A(0, 2);
    if (g) STG_B(0, 1, kx);
    BARW(); MFMA16(2); BARP();
    // ---- ph4: X m-pair3; vmcnt forces Y=KT(2i+1) complete ----
    READ_A(0, 3);
    BARW(); MFMA16(3);
    if (g) asm volatile("s_waitcnt vmcnt(4)" ::: "memory");
    else   asm volatile("s_waitcnt vmcnt(0)" ::: "memory");
    BARP();
    // ---- ph5: Y m-pair0; stage X'.A0+A1 [X.A free after ph4] ----
    READ_A(1, 0); READ_B(1);
    if (g) { STG_A(0, 0, kx); STG_A(0, 1, kx); }
    BARW(); MFMA16(0); BARP();
    // ---- ph6: Y m-pair1; stage Y'.B0 [Y.B free after ph5] ----
    READ_A(1, 1);
    if (g) STG_B(1, 0, ky);
    BARW(); MFMA16(1); BARP();
    // ---- ph7: Y m-pair2; stage Y'.B1 ----
    READ_A(1, 2);
    if (g) STG_B(1, 1, ky);
    BARW(); MFMA16(2); BARP();
    // ---- ph8: Y m-pair3; vmcnt forces X'=KT(2i+2) complete ----
    READ_A(1, 3);
    BARW(); MFMA16(3);
    if (g) asm volatile("s_waitcnt vmcnt(4)" ::: "memory");
    BARP();
  }
#undef STG_A
#undef STG_B
#undef READ_A
#undef READ_B

  // ===== epilogue: g = relu(acc+b1) -> LDS [256][256] bf16 (swizzled), then g x V^T =====
#pragma unroll
  for (int n = 0; n < 4; ++n) {
    const int lcol = wc * 64 + n * 16 + fr;
    const float bias = b1[(size_t)e * kH + bcol + lcol];
    const int cbyte = (lcol >> 3) << 4;
#pragma unroll
    for (int m = 0; m < 8; ++m) {
#pragma unroll
      for (int j = 0; j < 4; ++j) {
        const int lrow = wr * 128 + m * 16 + jg * 4 + j;
        const float v = fmaxf(acc[m][n][j] + bias, 0.f);
        *reinterpret_cast<unsigned short*>(
            smem + lrow * 512 + (cbyte ^ ((lrow & 7) << 4)) + (fr & 7) * 2) = f2bf(v);
      }
    }
  }
  asm volatile("s_waitcnt lgkmcnt(0)\ns_barrier" ::: "memory");

  // small GEMM: 16 row-groups of 16; contract 256 h-cols (8 x K32) with Vt
  const unsigned short* const VtE = Vt + (size_t)e * 16 * kH + (size_t)fr * kH + bcol;
  bf16x8 gv[8];
#pragma unroll
  for (int kk = 0; kk < 8; ++kk)
    gv[kk] = *reinterpret_cast<const bf16x8*>(VtE + kk * 32 + jg * 8);
#pragma unroll
  for (int f = 0; f < 2; ++f) {
    const int rowl = (2 * w + f) * 16 + fr;
    f32x4 pc = (f32x4){0.f, 0.f, 0.f, 0.f};
#pragma unroll
    for (int kk = 0; kk < 8; ++kk) {
      bf16x8 ga = *reinterpret_cast<const bf16x8*>(
          smem + rowl * 512 + ((((kk * 4 + jg)) ^ (rowl & 7)) << 4));
      pc = __builtin_amdgcn_mfma_f32_16x16x32_bf16(ga, gv[kk], pc, 0, 0, 0);
    }
    const int rowg = brow + (2 * w + f) * 16 + jg * 4;
#pragma unroll
    for (int j = 0; j < 4; ++j) {
      const float val = pc[j] * rr[(size_t)(rowg + j) * kE + e];
      atomicAdd(&part[(size_t)(rowg + j) * 16 + fr], val);
    }
  }
}

// ------- combine: y[b][c] = part[b][c] + sum_e r[b][e]*u[e][c] + bc[c] -------
__global__ __launch_bounds__(256) void k_combine(const float* __restrict__ part,
                                                 const float* __restrict__ rr,
                                                 const float* __restrict__ u,
                                                 const float* __restrict__ bc,
                                                 float* __restrict__ y) {
  const int tid = threadIdx.x;
  const int rloc = tid >> 4, c = tid & 15;
  const int b = blockIdx.x * 16 + rloc;
  if (c >= kC) return;
  float acc = part[(size_t)b * 16 + c] + bc[c];
#pragma unroll
  for (int e = 0; e < kE; ++e) acc += rr[(size_t)b * kE + e] * u[e * 16 + c];
  y[(size_t)b * kC + c] = acc;
}

extern "C" void kernel_launch(void* const* d_in, const int* in_sizes, int n_in,
                              void* d_out, int out_size, void* d_ws, size_t ws_size,
                              hipStream_t stream) {
  (void)in_sizes; (void)n_in; (void)out_size; (void)ws_size;
  const float* x  = (const float*)d_in[0];
  const float* Wr = (const float*)d_in[1];
  const float* br = (const float*)d_in[2];
  const float* W1 = (const float*)d_in[3];
  const float* b1 = (const float*)d_in[4];
  const float* W2 = (const float*)d_in[5];
  const float* b2 = (const float*)d_in[6];
  const float* Wc = (const float*)d_in[7];
  const float* bc = (const float*)d_in[8];
  float* y = (float*)d_out;

  // workspace carve (~82 MB)
  char* p = (char*)d_ws;
  unsigned short* xb  = (unsigned short*)p; p += (size_t)kB * kD * 2;        // 16 MB
  unsigned short* W1t = (unsigned short*)p; p += (size_t)kE * kH * kD * 2;   // 64 MB
  unsigned short* Vt  = (unsigned short*)p; p += (size_t)kE * 16 * kH * 2;   // 1 MB
  float* r    = (float*)p;                  p += (size_t)kB * kE * 4;        // 256 KB
  float* u    = (float*)p;                  p += (size_t)kE * 16 * 4;        // 512 B
  float* part = (float*)p;                  p += (size_t)kB * 16 * 4;        // 512 KB

  k_convert_x<<<dim3(kB * kD / 8 / 256), dim3(256), 0, stream>>>(x, xb);
  k_routing<<<dim3(kB / 4), dim3(256), 0, stream>>>(x, Wr, br, r);
  k_transpose_w<<<dim3(kH / 32, kD / 32, kE), dim3(32, 8), 0, stream>>>(W1, W1t, kD, kH);
  k_vbuild<<<dim3(kE * kH / 128), dim3(128), 0, stream>>>(W2, Wc, Vt);
  k_ubuild<<<dim3(1), dim3(128), 0, stream>>>(b2, Wc, u);
  k_zero_f32<<<dim3(kB * 16 / 256), dim3(256), 0, stream>>>(part);

  k_moe_fused256<<<dim3(kB / 256, kH / 256, kE), dim3(512), 0, stream>>>(
      xb, W1t, b1, Vt, r, part);

  k_combine<<<dim3(kB / 16), dim3(256), 0, stream>>>(part, r, u, bc, y);
}